// Round 5
// baseline (258.411 us; speedup 1.0000x reference)
//
#include <hip/hip_runtime.h>
#include <hip/hip_bf16.h>

#define ALPHA 0.2f
constexpr int N = 2048;
constexpr int H = 4;
constexpr int NW = N / 64;     // 32 mask words per row

typedef __attribute__((ext_vector_type(8))) short short8v;  // bf16 bits x8
typedef __attribute__((ext_vector_type(4))) float f32x4;

__device__ inline unsigned short bf16_rne(float f) {
  unsigned u = __float_as_uint(f);
  return (unsigned short)((u + 0x7fffu + ((u >> 16) & 1u)) >> 16);
}
// order-preserving uint encoding of float (for atomicMax); init sentinel 0 == -inf
__device__ inline unsigned enc_ord(float f) {
  unsigned b = __float_as_uint(f);
  return (b & 0x80000000u) ? ~b : (b | 0x80000000u);
}
__device__ inline float dec_ord(unsigned u) {
  unsigned b = (u & 0x80000000u) ? (u ^ 0x80000000u) : ~u;
  return __uint_as_float(b);
}

// ---------------- pack adjacency into bitmask; also init mh_u ----------------
__global__ void pack_adj_kernel(const int* __restrict__ adj, unsigned long long* __restrict__ mask,
                                unsigned* __restrict__ mh_u) {
  if (blockIdx.x == 0 && threadIdx.x < 24) mh_u[threadIdx.x] = 0u;
  int word = blockIdx.x * 4 + (threadIdx.x >> 6);
  int lane = threadIdx.x & 63;
  unsigned long long b = __ballot(adj[(size_t)word * 64 + lane] != 0);
  if (lane == 0) mask[word] = b;
}

// ---------------- fused encoder + layer-0 projection + s-max tail ----------------
__global__ void enc_h0_kernel(const float* __restrict__ nf,
                              const float* __restrict__ W1, const float* __restrict__ b1,
                              const float* __restrict__ W2, const float* __restrict__ b2,
                              const float* __restrict__ W0, const float* __restrict__ a0,
                              __hip_bfloat16* __restrict__ hT,
                              float* __restrict__ s1, float* __restrict__ s2,
                              unsigned* __restrict__ mh_u) {
  const int n0 = blockIdx.x * 4;
  const int j = threadIdx.x >> 6, o = threadIdx.x & 63; // j doubles as head later
  __shared__ float nfs[4][10];
  __shared__ float x1[4][64];
  __shared__ float xs[4][64];
  if (threadIdx.x < 40) nfs[threadIdx.x / 10][threadIdx.x % 10] = nf[n0 * 10 + threadIdx.x];
  __syncthreads();
  float acc = b1[o];
#pragma unroll
  for (int k = 0; k < 10; k++) acc = fmaf(nfs[j][k], W1[k * 64 + o], acc);
  x1[j][o] = fmaxf(acc, 0.f);
  __syncthreads();
  float acc2 = b2[o];
#pragma unroll 8
  for (int k = 0; k < 64; k++) acc2 = fmaf(x1[j][k], W2[k * 64 + o], acc2);
  xs[j][o] = acc2;
  __syncthreads();
  const int head = j;
  const float* __restrict__ Wh = W0 + (size_t)head * 64 * 64;
  float ah[4] = {0.f, 0.f, 0.f, 0.f};
#pragma unroll 8
  for (int k = 0; k < 64; k++) {
    float wv = Wh[k * 64 + o];
    ah[0] = fmaf(xs[0][k], wv, ah[0]);
    ah[1] = fmaf(xs[1][k], wv, ah[1]);
    ah[2] = fmaf(xs[2][k], wv, ah[2]);
    ah[3] = fmaf(xs[3][k], wv, ah[3]);
  }
  const float aa1 = a0[head * 128 + o];
  const float aa2 = a0[head * 128 + 64 + o];
  ushort4 pk;
  unsigned short* pkp = (unsigned short*)&pk;
  float m1 = -3.4e38f, m2 = -3.4e38f;
#pragma unroll
  for (int jj = 0; jj < 4; jj++) {
    pkp[jj] = bf16_rne(ah[jj]);
    float p1 = ah[jj] * aa1, p2 = ah[jj] * aa2;
    for (int s = 32; s; s >>= 1) { p1 += __shfl_xor(p1, s); p2 += __shfl_xor(p2, s); }
    m1 = fmaxf(m1, p1); m2 = fmaxf(m2, p2);
    if (o == 0) { s1[head * N + n0 + jj] = p1; s2[head * N + n0 + jj] = p2; }
  }
  if (o == 0) {
    atomicMax(&mh_u[head], enc_ord(m1));
    atomicMax(&mh_u[4 + head], enc_ord(m2));
  }
  *(ushort4*)((unsigned short*)hT + ((size_t)head * 64 + o) * N + n0) = pk;
}

// ---------------- layer-1 projection (in_f=256) + s-max tail ----------------
__global__ void h_all_kernel(const float* __restrict__ x, const float* __restrict__ W,
                             const float* __restrict__ a,
                             __hip_bfloat16* __restrict__ hT,
                             float* __restrict__ s1, float* __restrict__ s2,
                             unsigned* __restrict__ mh_u) {
  const int n0 = blockIdx.x * 4;
  const int head = threadIdx.x >> 6, o = threadIdx.x & 63;
  __shared__ float xr[4][256];
  for (int k = threadIdx.x; k < 1024; k += 256) xr[k >> 8][k & 255] = x[(size_t)n0 * 256 + k];
  __syncthreads();
  const float* __restrict__ Wh = W + (size_t)head * 256 * 64;
  float ah[4] = {0.f, 0.f, 0.f, 0.f};
#pragma unroll 4
  for (int k = 0; k < 256; k++) {
    float wv = Wh[k * 64 + o];
    ah[0] = fmaf(xr[0][k], wv, ah[0]);
    ah[1] = fmaf(xr[1][k], wv, ah[1]);
    ah[2] = fmaf(xr[2][k], wv, ah[2]);
    ah[3] = fmaf(xr[3][k], wv, ah[3]);
  }
  const float aa1 = a[head * 128 + o];
  const float aa2 = a[head * 128 + 64 + o];
  ushort4 pk;
  unsigned short* pkp = (unsigned short*)&pk;
  float m1 = -3.4e38f, m2 = -3.4e38f;
#pragma unroll
  for (int jj = 0; jj < 4; jj++) {
    pkp[jj] = bf16_rne(ah[jj]);
    float p1 = ah[jj] * aa1, p2 = ah[jj] * aa2;
    for (int s = 32; s; s >>= 1) { p1 += __shfl_xor(p1, s); p2 += __shfl_xor(p2, s); }
    m1 = fmaxf(m1, p1); m2 = fmaxf(m2, p2);
    if (o == 0) { s1[head * N + n0 + jj] = p1; s2[head * N + n0 + jj] = p2; }
  }
  if (o == 0) {
    atomicMax(&mh_u[8 + head], enc_ord(m1));
    atomicMax(&mh_u[12 + head], enc_ord(m2));
  }
  *(ushort4*)((unsigned short*)hT + ((size_t)head * 64 + o) * N + n0) = pk;
}

// ---------------- fused MFMA aggregation + denom + normalize + ELU + concat ----------------
// grid (N/16, H), block 512 = 8 waves; wave w = K-chunk of 256 q. Writes xout [n][H*64].
__global__ void __launch_bounds__(512, 4)
agg_fused_kernel(const __hip_bfloat16* __restrict__ hT,
                 const float* __restrict__ s1, const float* __restrict__ s2,
                 const unsigned* __restrict__ mh_u, const int moff,
                 const unsigned long long* __restrict__ mask,
                 float* __restrict__ xout) {
  const int head = blockIdx.y;
  const int p0 = blockIdx.x * 16;
  const int wave = threadIdx.x >> 6, lane = threadIdx.x & 63;
  const int col = lane & 15, kgrp = lane >> 4;
  const int p = p0 + col;
  const float s2p = s2[head * N + p];
  float mm = dec_ord(mh_u[moff + head]) + dec_ord(mh_u[moff + 4 + head]);
  const float mhv = fmaxf(mm, ALPHA * mm);
  const float* __restrict__ s1h = s1 + head * N;
  const int qbase = wave * 256;
  const unsigned long long* __restrict__ mr = mask + (size_t)p * NW + (qbase >> 6);
  unsigned long long mw0 = mr[0], mw1 = mr[1], mw2 = mr[2], mw3 = mr[3];
  const unsigned short* __restrict__ hTu = (const unsigned short*)hT;
  size_t boff[4];
#pragma unroll
  for (int ff = 0; ff < 4; ff++) boff[ff] = ((size_t)head * 64 + ff * 16 + col) * N;

  f32x4 acc[4] = {{0,0,0,0},{0,0,0,0},{0,0,0,0},{0,0,0,0}};
  float wsum = 0.f;
#pragma unroll
  for (int ks = 0; ks < 8; ks++) {
    const int qa = qbase + ks * 32 + kgrp * 8;
    float4 s1v0 = *(const float4*)(s1h + qa);
    float4 s1v1 = *(const float4*)(s1h + qa + 4);
    unsigned long long mwsel = (ks < 2) ? mw0 : (ks < 4) ? mw1 : (ks < 6) ? mw2 : mw3;
    unsigned b8 = (unsigned)((mwsel >> ((ks & 1) * 32 + kgrp * 8)) & 0xFFull);
    float sv[8] = {s1v0.x, s1v0.y, s1v0.z, s1v0.w, s1v1.x, s1v1.y, s1v1.z, s1v1.w};
    short8v a_hi, a_lo;
#pragma unroll
    for (int e = 0; e < 8; e++) {
      float ev = sv[e] + s2p;
      float lr = fmaxf(ev, ALPHA * ev);
      float w = ((b8 >> e) & 1u) ? __expf(lr - mhv) : 0.f;
      wsum += w;
      unsigned short hb = bf16_rne(w);
      float hf = __uint_as_float((unsigned)hb << 16);
      a_hi[e] = (short)hb;
      a_lo[e] = (short)bf16_rne(w - hf);
    }
#pragma unroll
    for (int ff = 0; ff < 4; ff++) {
      short8v b_hi = *(const short8v*)(hTu + boff[ff] + qa);
      acc[ff] = __builtin_amdgcn_mfma_f32_16x16x32_bf16(a_hi, b_hi, acc[ff], 0, 0, 0);
      acc[ff] = __builtin_amdgcn_mfma_f32_16x16x32_bf16(a_lo, b_hi, acc[ff], 0, 0, 0);
    }
  }
  wsum += __shfl_xor(wsum, 16);
  wsum += __shfl_xor(wsum, 32);

  __shared__ float red[8][16][65];
  __shared__ float wred[8][16];
#pragma unroll
  for (int ff = 0; ff < 4; ff++)
#pragma unroll
    for (int r = 0; r < 4; r++)
      red[wave][kgrp * 4 + r][ff * 16 + col] = acc[ff][r];
  if (lane < 16) wred[wave][lane] = wsum;
  __syncthreads();
#pragma unroll
  for (int rep = 0; rep < 2; rep++) {
    int idx = threadIdx.x + rep * 512;
    int pl = idx >> 6, f = idx & 63;
    float num = 0.f, dn = 0.f;
#pragma unroll
    for (int w = 0; w < 8; w++) { num += red[w][pl][f]; dn += wred[w][pl]; }
    float v = num / dn;
    v = v > 0.f ? v : (__expf(v) - 1.f);
    xout[(size_t)(p0 + pl) * 256 + head * 64 + f] = v;
  }
}

// ---------------- layer-2 projection (F_out=3), 4 nodes/block, + s-max tail ----------------
__global__ void h3_kernel(const float* __restrict__ x, const float* __restrict__ W,
                          const float* __restrict__ a, float* __restrict__ h2,
                          float* __restrict__ s1, float* __restrict__ s2,
                          unsigned* __restrict__ mh_u) {
  const int n0 = blockIdx.x * 4;
  const int head = threadIdx.x >> 6, o = threadIdx.x & 63;
  __shared__ float xr[4][256];
  for (int k = threadIdx.x; k < 1024; k += 256) xr[k >> 8][k & 255] = x[(size_t)n0 * 256 + k];
  __syncthreads();
  const float* __restrict__ Wh = W + (size_t)head * 256 * 3;
  float m1 = -3.4e38f, m2 = -3.4e38f;
#pragma unroll
  for (int jj = 0; jj < 4; jj++) {
    float a0 = 0.f, a1 = 0.f, a2 = 0.f;
#pragma unroll
    for (int i = 0; i < 4; i++) {
      int k = o + 64 * i;
      float xv = xr[jj][k];
      a0 = fmaf(xv, Wh[k * 3 + 0], a0);
      a1 = fmaf(xv, Wh[k * 3 + 1], a1);
      a2 = fmaf(xv, Wh[k * 3 + 2], a2);
    }
    for (int s = 32; s; s >>= 1) {
      a0 += __shfl_xor(a0, s); a1 += __shfl_xor(a1, s); a2 += __shfl_xor(a2, s);
    }
    float p1 = a0 * a[head * 6 + 0] + a1 * a[head * 6 + 1] + a2 * a[head * 6 + 2];
    float p2 = a0 * a[head * 6 + 3] + a1 * a[head * 6 + 4] + a2 * a[head * 6 + 5];
    m1 = fmaxf(m1, p1); m2 = fmaxf(m2, p2);
    if (o == 0) {
      float* hq = h2 + ((size_t)head * N + n0 + jj) * 3;
      hq[0] = a0; hq[1] = a1; hq[2] = a2;
      s1[head * N + n0 + jj] = p1;
      s2[head * N + n0 + jj] = p2;
    }
  }
  if (o == 0) {
    atomicMax(&mh_u[16 + head], enc_ord(m1));
    atomicMax(&mh_u[20 + head], enc_ord(m2));
  }
}

// ---------------- layer-2 aggregation, self-normalizing, fused head-mean + ELU -> emb ----------------
__global__ void agg2_kernel(const float* __restrict__ h2, const float* __restrict__ s1,
                            const float* __restrict__ s2, const unsigned* __restrict__ mh_u,
                            const unsigned long long* __restrict__ mask,
                            float* __restrict__ emb) {
  const int p = blockIdx.x;
  const int head = threadIdx.x >> 6, lane = threadIdx.x & 63;
  const float s2p = s2[head * N + p];
  float mm = dec_ord(mh_u[16 + head]) + dec_ord(mh_u[20 + head]);
  const float mhv = fmaxf(mm, ALPHA * mm);
  const float* __restrict__ s1h = s1 + head * N;
  float a0 = 0.f, a1 = 0.f, a2 = 0.f, wsum = 0.f;
#pragma unroll 2
  for (int i = 0; i < 32; i++) {
    unsigned long long mwd = mask[(size_t)p * NW + i];
    int q = i * 64 + lane;
    if ((mwd >> lane) & 1ull) {
      float e = s1h[q] + s2p;
      e = fmaxf(e, ALPHA * e);
      float w = __expf(e - mhv);
      const float* __restrict__ hq = h2 + ((size_t)head * N + q) * 3;
      a0 = fmaf(w, hq[0], a0);
      a1 = fmaf(w, hq[1], a1);
      a2 = fmaf(w, hq[2], a2);
      wsum += w;
    }
  }
  for (int s = 32; s; s >>= 1) {
    a0 += __shfl_xor(a0, s); a1 += __shfl_xor(a1, s);
    a2 += __shfl_xor(a2, s); wsum += __shfl_xor(wsum, s);
  }
  __shared__ float red[4][4];
  if (lane == 0) { red[head][0] = a0; red[head][1] = a1; red[head][2] = a2; red[head][3] = wsum; }
  __syncthreads();
  if (threadIdx.x < 3) {
    int f = threadIdx.x;
    float v = 0.f;
#pragma unroll
    for (int hh = 0; hh < 4; hh++) v += red[hh][f] / red[hh][3];
    v *= 0.25f;
    v = v > 0.f ? v : (__expf(v) - 1.f);
    emb[p * 3 + f] = v;
  }
}

// ---------------- all-pairs edge classifier ----------------
__global__ void cls_kernel(const float* __restrict__ emb,
                           const float* __restrict__ W1, const float* __restrict__ b1,
                           const float* __restrict__ W2, const float* __restrict__ b2,
                           float* __restrict__ out) {
  int q = blockIdx.x * 256 + threadIdx.x;
  int p0 = blockIdx.y * 8;
  __shared__ float ep[8][3];
  __shared__ float w1s[96], b1s[32], w2s[32];
  __shared__ float b2s;
  int t = threadIdx.x;
  if (t < 96) w1s[t] = W1[t];
  else if (t < 128) b1s[t - 96] = b1[t - 96];
  else if (t < 160) w2s[t - 128] = W2[t - 128];
  else if (t == 160) b2s = b2[0];
  else if (t >= 192 && t < 216) ((float*)ep)[t - 192] = emb[p0 * 3 + t - 192];
  __syncthreads();
  float e0 = emb[q * 3 + 0], e1 = emb[q * 3 + 1], e2 = emb[q * 3 + 2];
  float d[8][3];
#pragma unroll
  for (int i = 0; i < 8; i++) {
    d[i][0] = fabsf(ep[i][0] - e0);
    d[i][1] = fabsf(ep[i][1] - e1);
    d[i][2] = fabsf(ep[i][2] - e2);
  }
  float acc[8] = {0, 0, 0, 0, 0, 0, 0, 0};
#pragma unroll
  for (int j = 0; j < 32; j++) {
    float c0 = w1s[j], c1 = w1s[32 + j], c2 = w1s[64 + j], bb = b1s[j], w2 = w2s[j];
#pragma unroll
    for (int i = 0; i < 8; i++) {
      float hv = fmaxf(bb + d[i][0] * c0 + d[i][1] * c1 + d[i][2] * c2, 0.f);
      acc[i] += hv * w2;
    }
  }
#pragma unroll
  for (int i = 0; i < 8; i++) {
    float x = acc[i] + b2s;
    out[(size_t)(p0 + i) * N + q] = 1.f / (1.f + __expf(-x));
  }
}

extern "C" void kernel_launch(void* const* d_in, const int* in_sizes, int n_in,
                              void* d_out, int out_size, void* d_ws, size_t ws_size,
                              hipStream_t stream) {
  const float* nf    = (const float*)d_in[0];
  const int*   adj   = (const int*)d_in[1];
  const float* encW1 = (const float*)d_in[2];
  const float* encb1 = (const float*)d_in[3];
  const float* encW2 = (const float*)d_in[4];
  const float* encb2 = (const float*)d_in[5];
  const float* gatW0 = (const float*)d_in[6];
  const float* gata0 = (const float*)d_in[7];
  const float* gatW1 = (const float*)d_in[8];
  const float* gata1 = (const float*)d_in[9];
  const float* gatW2 = (const float*)d_in[10];
  const float* gata2 = (const float*)d_in[11];
  const float* clsW1 = (const float*)d_in[12];
  const float* clsb1 = (const float*)d_in[13];
  const float* clsW2 = (const float*)d_in[14];
  const float* clsb2 = (const float*)d_in[15];

  float* ws = (float*)d_ws;
  __hip_bfloat16* hT = (__hip_bfloat16*)ws;      // bf16 [H][64][N] (1 MB)
  float* s1  = ws + 262144;                      // H*N
  float* s2  = s1 + 8192;
  unsigned* mh_u = (unsigned*)(s2 + 8192);       // 24 used (pad 64)
  float* xA  = (float*)(mh_u + 64);              // N*256
  float* xB  = xA + 524288;                      // N*256
  float* h2  = xB + 524288;                      // H*N*3
  unsigned long long* mask = (unsigned long long*)(h2 + 24576); // N*NW words (512 KB)

  float* emb = (float*)d_out;                    // 2048*3
  float* eprob = emb + N * 3;                    // 2048*2048

  pack_adj_kernel<<<dim3(N * NW / 4), dim3(256), 0, stream>>>(adj, mask, mh_u);

  // ---- GAT layer 0 ----
  enc_h0_kernel<<<dim3(N / 4), dim3(256), 0, stream>>>(nf, encW1, encb1, encW2, encb2,
                                                       gatW0, gata0, hT, s1, s2, mh_u);
  agg_fused_kernel<<<dim3(N / 16, H), dim3(512), 0, stream>>>(hT, s1, s2, mh_u, 0, mask, xA);

  // ---- GAT layer 1 ----
  h_all_kernel<<<dim3(N / 4), dim3(256), 0, stream>>>(xA, gatW1, gata1, hT, s1, s2, mh_u);
  agg_fused_kernel<<<dim3(N / 16, H), dim3(512), 0, stream>>>(hT, s1, s2, mh_u, 8, mask, xB);

  // ---- GAT layer 2 ----
  h3_kernel<<<dim3(N / 4), dim3(256), 0, stream>>>(xB, gatW2, gata2, h2, s1, s2, mh_u);
  agg2_kernel<<<dim3(N), dim3(256), 0, stream>>>(h2, s1, s2, mh_u, mask, emb);

  // ---- classifier ----
  cls_kernel<<<dim3(8, N / 8), dim3(256), 0, stream>>>(emb, clsW1, clsb1, clsW2, clsb2, eprob);
}

// Round 6
// 115.809 us; speedup vs baseline: 2.2314x; 2.2314x over previous
//
#include <hip/hip_runtime.h>
#include <hip/hip_bf16.h>

#define ALPHA 0.2f
constexpr int N = 2048;
constexpr int H = 4;
constexpr int NW = N / 64;     // 32 mask words per row

typedef __attribute__((ext_vector_type(8))) short short8v;  // bf16 bits x8
typedef __attribute__((ext_vector_type(4))) float f32x4;

__device__ inline unsigned short bf16_rne(float f) {
  unsigned u = __float_as_uint(f);
  return (unsigned short)((u + 0x7fffu + ((u >> 16) & 1u)) >> 16);
}

// ---------------- pack adjacency into bitmask ----------------
__global__ void pack_adj_kernel(const int* __restrict__ adj, unsigned long long* __restrict__ mask) {
  int word = blockIdx.x * 4 + (threadIdx.x >> 6);
  int lane = threadIdx.x & 63;
  unsigned long long b = __ballot(adj[(size_t)word * 64 + lane] != 0);
  if (lane == 0) mask[word] = b;
}

// ---------------- W prep: transpose + bf16 hi/lo split ----------------
// W0 [4][64][64] -> WT0 [4][o=64][k=64]; W1 [4][256][64] -> WT1 [4][o=64][k=256]
__global__ void wprep_kernel(const float* __restrict__ W0, const float* __restrict__ W1,
                             unsigned short* __restrict__ wt0hi, unsigned short* __restrict__ wt0lo,
                             unsigned short* __restrict__ wt1hi, unsigned short* __restrict__ wt1lo) {
  int bx = blockIdx.x, t = threadIdx.x;
  if (bx < 4) {
    int head = bx;
    for (int idx = t; idx < 64 * 64; idx += 256) {
      int o = idx >> 6, k = idx & 63;
      float v = W0[(head * 64 + k) * 64 + o];
      unsigned short hb = bf16_rne(v);
      float hf = __uint_as_float((unsigned)hb << 16);
      wt0hi[head * 4096 + idx] = hb;          // [head][o][k], idx = o*64+k
      wt0lo[head * 4096 + idx] = bf16_rne(v - hf);
    }
  } else {
    int b = bx - 4;  // 16 blocks: 4 per head
    int head = b >> 2, part = b & 3;
    for (int idx = t; idx < 16 * 256; idx += 256) {
      int o = part * 16 + (idx >> 8);
      int k = idx & 255;
      float v = W1[((size_t)head * 256 + k) * 64 + o];
      unsigned short hb = bf16_rne(v);
      float hf = __uint_as_float((unsigned)hb << 16);
      size_t oidx = ((size_t)head * 64 + o) * 256 + k;
      wt1hi[oidx] = hb;
      wt1lo[oidx] = bf16_rne(v - hf);
    }
  }
}

// ---------------- encoder MLP only: x0 = relu(nf@W1+b1)@W2+b2, bf16 hi/lo out ----------------
__global__ void enc_kernel(const float* __restrict__ nf,
                           const float* __restrict__ W1, const float* __restrict__ b1,
                           const float* __restrict__ W2, const float* __restrict__ b2,
                           unsigned short* __restrict__ xhi, unsigned short* __restrict__ xlo) {
  const int n0 = blockIdx.x * 4;
  const int t = threadIdx.x;
  const int j = t >> 6, o = t & 63;
  __shared__ float nfs[4][10];
  __shared__ float x1[4][64];
  __shared__ float pred[4][4][64];  // [kq][node][o]
  if (t < 40) nfs[t / 10][t % 10] = nf[n0 * 10 + t];
  __syncthreads();
  float acc = b1[o];
#pragma unroll
  for (int k = 0; k < 10; k++) acc = fmaf(nfs[j][k], W1[k * 64 + o], acc);
  x1[j][o] = fmaxf(acc, 0.f);
  __syncthreads();
  {  // phase 2: j = k-quarter; each W2 load feeds 4 nodes
    const int kq = j;
    float pp0 = 0, pp1 = 0, pp2 = 0, pp3 = 0;
#pragma unroll
    for (int kk = 0; kk < 16; kk++) {
      int k = kq * 16 + kk;
      float wv = W2[k * 64 + o];
      pp0 = fmaf(x1[0][k], wv, pp0);
      pp1 = fmaf(x1[1][k], wv, pp1);
      pp2 = fmaf(x1[2][k], wv, pp2);
      pp3 = fmaf(x1[3][k], wv, pp3);
    }
    pred[kq][0][o] = pp0; pred[kq][1][o] = pp1;
    pred[kq][2][o] = pp2; pred[kq][3][o] = pp3;
  }
  __syncthreads();
  float v = b2[o] + pred[0][j][o] + pred[1][j][o] + pred[2][j][o] + pred[3][j][o];
  unsigned short hb = bf16_rne(v);
  float hf = __uint_as_float((unsigned)hb << 16);
  xhi[(n0 + j) * 64 + o] = hb;
  xlo[(n0 + j) * 64 + o] = bf16_rne(v - hf);
}

// ---------------- MFMA projection: hT[head][o][n] = (x @ W)^T, + s1/s2 + per-tile s1 max ----------------
// grid (N/16 = 128, H), block 256 = 4 waves; wave = o-strip of 16. 3-term hi/lo MFMA.
template <int K>
__global__ void __launch_bounds__(256, 4)
proj_mfma_kernel(const unsigned short* __restrict__ xhi, const unsigned short* __restrict__ xlo,
                 const unsigned short* __restrict__ wthi, const unsigned short* __restrict__ wtlo,
                 const float* __restrict__ avec,
                 unsigned short* __restrict__ hT, float* __restrict__ s1, float* __restrict__ s2,
                 float* __restrict__ pm1) {
  const int head = blockIdx.y;
  const int n0 = blockIdx.x * 16;
  const int wave = threadIdx.x >> 6, lane = threadIdx.x & 63;
  const int il = lane & 15, kgrp = lane >> 4;
  const int o0 = wave * 16;
  const unsigned short* __restrict__ Ah = wthi + ((size_t)head * 64 + o0 + il) * K;
  const unsigned short* __restrict__ Al = wtlo + ((size_t)head * 64 + o0 + il) * K;
  const unsigned short* __restrict__ Bh = xhi + (size_t)(n0 + il) * K;
  const unsigned short* __restrict__ Bl = xlo + (size_t)(n0 + il) * K;
  f32x4 acc = {0, 0, 0, 0};
#pragma unroll
  for (int ks = 0; ks < K / 32; ks++) {
    const int ka = ks * 32 + kgrp * 8;
    short8v ah = *(const short8v*)(Ah + ka);
    short8v al = *(const short8v*)(Al + ka);
    short8v bh = *(const short8v*)(Bh + ka);
    short8v bl = *(const short8v*)(Bl + ka);
    acc = __builtin_amdgcn_mfma_f32_16x16x32_bf16(ah, bh, acc, 0, 0, 0);
    acc = __builtin_amdgcn_mfma_f32_16x16x32_bf16(al, bh, acc, 0, 0, 0);
    acc = __builtin_amdgcn_mfma_f32_16x16x32_bf16(ah, bl, acc, 0, 0, 0);
  }
  // D: row(o_local) = kgrp*4+r, col(n_local) = il
  const int n = n0 + il;
  float p1 = 0.f, p2 = 0.f;
#pragma unroll
  for (int r = 0; r < 4; r++) {
    const int o = o0 + kgrp * 4 + r;
    hT[((size_t)head * 64 + o) * N + n] = bf16_rne(acc[r]);
    p1 = fmaf(acc[r], avec[head * 128 + o], p1);
    p2 = fmaf(acc[r], avec[head * 128 + 64 + o], p2);
  }
  p1 += __shfl_xor(p1, 16); p1 += __shfl_xor(p1, 32);
  p2 += __shfl_xor(p2, 16); p2 += __shfl_xor(p2, 32);
  __shared__ float s1p[4][16], s2p[4][16];
  if (kgrp == 0) { s1p[wave][il] = p1; s2p[wave][il] = p2; }
  __syncthreads();
  if (threadIdx.x < 16) {
    int nn = n0 + threadIdx.x;
    float v1 = s1p[0][threadIdx.x] + s1p[1][threadIdx.x] + s1p[2][threadIdx.x] + s1p[3][threadIdx.x];
    float v2 = s2p[0][threadIdx.x] + s2p[1][threadIdx.x] + s2p[2][threadIdx.x] + s2p[3][threadIdx.x];
    s1[head * N + nn] = v1;
    s2[head * N + nn] = v2;
    float m1 = v1;
#pragma unroll
    for (int s = 1; s < 16; s <<= 1) m1 = fmaxf(m1, __shfl_xor(m1, s));
    if (threadIdx.x == 0) pm1[head * 128 + blockIdx.x] = m1;
  }
}

// ---------------- fused MFMA aggregation + denom + normalize + ELU + concat ----------------
// grid (N/16, H), block 512 = 8 waves; wave w = K-chunk of 256 q. Writes xout [n][256] (+hi/lo bf16).
__global__ void __launch_bounds__(512, 4)
agg_fused_kernel(const unsigned short* __restrict__ hTu,
                 const float* __restrict__ s1, const float* __restrict__ s2,
                 const float* __restrict__ pm1,
                 const unsigned long long* __restrict__ mask,
                 float* __restrict__ xout,
                 unsigned short* __restrict__ xohi, unsigned short* __restrict__ xolo) {
  const int head = blockIdx.y;
  const int p0 = blockIdx.x * 16;
  const int wave = threadIdx.x >> 6, lane = threadIdx.x & 63;
  const int col = lane & 15, kgrp = lane >> 4;
  const int p = p0 + col;
  const float s2p = s2[head * N + p];
  // s1 max for this head from 128 per-tile partials (all waves redundantly)
  float sm = fmaxf(pm1[head * 128 + lane], pm1[head * 128 + 64 + lane]);
#pragma unroll
  for (int s = 1; s < 64; s <<= 1) sm = fmaxf(sm, __shfl_xor(sm, s));
  const float mraw = sm + s2p;
  const float mp = fmaxf(mraw, ALPHA * mraw);  // per-row shift (exact bound)
  const float* __restrict__ s1h = s1 + head * N;
  const int qbase = wave * 256;
  const unsigned long long* __restrict__ mr = mask + (size_t)p * NW + (qbase >> 6);
  unsigned long long mw0 = mr[0], mw1 = mr[1], mw2 = mr[2], mw3 = mr[3];
  size_t boff[4];
#pragma unroll
  for (int ff = 0; ff < 4; ff++) boff[ff] = ((size_t)head * 64 + ff * 16 + col) * N;

  f32x4 acc[4] = {{0,0,0,0},{0,0,0,0},{0,0,0,0},{0,0,0,0}};
  float wsum = 0.f;
#pragma unroll
  for (int ks = 0; ks < 8; ks++) {
    const int qa = qbase + ks * 32 + kgrp * 8;
    float4 s1v0 = *(const float4*)(s1h + qa);
    float4 s1v1 = *(const float4*)(s1h + qa + 4);
    unsigned long long mwsel = (ks < 2) ? mw0 : (ks < 4) ? mw1 : (ks < 6) ? mw2 : mw3;
    unsigned b8 = (unsigned)((mwsel >> ((ks & 1) * 32 + kgrp * 8)) & 0xFFull);
    float sv[8] = {s1v0.x, s1v0.y, s1v0.z, s1v0.w, s1v1.x, s1v1.y, s1v1.z, s1v1.w};
    short8v a_hi, a_lo;
#pragma unroll
    for (int e = 0; e < 8; e++) {
      float ev = sv[e] + s2p;
      float lr = fmaxf(ev, ALPHA * ev);
      float w = ((b8 >> e) & 1u) ? __expf(lr - mp) : 0.f;
      wsum += w;
      unsigned short hb = bf16_rne(w);
      float hf = __uint_as_float((unsigned)hb << 16);
      a_hi[e] = (short)hb;
      a_lo[e] = (short)bf16_rne(w - hf);
    }
#pragma unroll
    for (int ff = 0; ff < 4; ff++) {
      short8v b_hi = *(const short8v*)(hTu + boff[ff] + qa);
      acc[ff] = __builtin_amdgcn_mfma_f32_16x16x32_bf16(a_hi, b_hi, acc[ff], 0, 0, 0);
      acc[ff] = __builtin_amdgcn_mfma_f32_16x16x32_bf16(a_lo, b_hi, acc[ff], 0, 0, 0);
    }
  }
  wsum += __shfl_xor(wsum, 16);
  wsum += __shfl_xor(wsum, 32);

  __shared__ float red[8][16][65];
  __shared__ float wred[8][16];
#pragma unroll
  for (int ff = 0; ff < 4; ff++)
#pragma unroll
    for (int r = 0; r < 4; r++)
      red[wave][kgrp * 4 + r][ff * 16 + col] = acc[ff][r];
  if (lane < 16) wred[wave][lane] = wsum;
  __syncthreads();
#pragma unroll
  for (int rep = 0; rep < 2; rep++) {
    int idx = threadIdx.x + rep * 512;
    int pl = idx >> 6, f = idx & 63;
    float num = 0.f, dn = 0.f;
#pragma unroll
    for (int w = 0; w < 8; w++) { num += red[w][pl][f]; dn += wred[w][pl]; }
    float v = num / dn;
    v = v > 0.f ? v : (__expf(v) - 1.f);
    size_t oi = (size_t)(p0 + pl) * 256 + head * 64 + f;
    xout[oi] = v;
    if (xohi) {
      unsigned short hb = bf16_rne(v);
      float hf = __uint_as_float((unsigned)hb << 16);
      xohi[oi] = hb;
      xolo[oi] = bf16_rne(v - hf);
    }
  }
}

// ---------------- layer-2 projection (F_out=3), 4 nodes/block, per-tile s1 max ----------------
__global__ void h3_kernel(const float* __restrict__ x, const float* __restrict__ W,
                          const float* __restrict__ a, float* __restrict__ h2,
                          float* __restrict__ s1, float* __restrict__ s2,
                          float* __restrict__ pm1h3) {
  const int n0 = blockIdx.x * 4;
  const int head = threadIdx.x >> 6, o = threadIdx.x & 63;
  __shared__ float xr[4][256];
  for (int k = threadIdx.x; k < 1024; k += 256) xr[k >> 8][k & 255] = x[(size_t)n0 * 256 + k];
  __syncthreads();
  const float* __restrict__ Wh = W + (size_t)head * 256 * 3;
  float m1 = -3.4e38f;
#pragma unroll
  for (int jj = 0; jj < 4; jj++) {
    float a0 = 0.f, a1 = 0.f, a2 = 0.f;
#pragma unroll
    for (int i = 0; i < 4; i++) {
      int k = o + 64 * i;
      float xv = xr[jj][k];
      a0 = fmaf(xv, Wh[k * 3 + 0], a0);
      a1 = fmaf(xv, Wh[k * 3 + 1], a1);
      a2 = fmaf(xv, Wh[k * 3 + 2], a2);
    }
    for (int s = 32; s; s >>= 1) {
      a0 += __shfl_xor(a0, s); a1 += __shfl_xor(a1, s); a2 += __shfl_xor(a2, s);
    }
    float p1 = a0 * a[head * 6 + 0] + a1 * a[head * 6 + 1] + a2 * a[head * 6 + 2];
    float p2 = a0 * a[head * 6 + 3] + a1 * a[head * 6 + 4] + a2 * a[head * 6 + 5];
    m1 = fmaxf(m1, p1);
    if (o == 0) {
      float* hq = h2 + ((size_t)head * N + n0 + jj) * 3;
      hq[0] = a0; hq[1] = a1; hq[2] = a2;
      s1[head * N + n0 + jj] = p1;
      s2[head * N + n0 + jj] = p2;
    }
  }
  if (o == 0) pm1h3[head * 512 + blockIdx.x] = m1;
}

// ---------------- layer-2 aggregation, self-normalizing, fused head-mean + ELU -> emb ----------------
__global__ void agg2_kernel(const float* __restrict__ h2, const float* __restrict__ s1,
                            const float* __restrict__ s2, const float* __restrict__ pm1h3,
                            const unsigned long long* __restrict__ mask,
                            float* __restrict__ emb) {
  const int p = blockIdx.x;
  const int head = threadIdx.x >> 6, lane = threadIdx.x & 63;
  const float s2p = s2[head * N + p];
  float sm = -3.4e38f;
  for (int i = lane; i < 512; i += 64) sm = fmaxf(sm, pm1h3[head * 512 + i]);
#pragma unroll
  for (int s = 1; s < 64; s <<= 1) sm = fmaxf(sm, __shfl_xor(sm, s));
  float mraw = sm + s2p;
  const float mhv = fmaxf(mraw, ALPHA * mraw);
  const float* __restrict__ s1h = s1 + head * N;
  float a0 = 0.f, a1 = 0.f, a2 = 0.f, wsum = 0.f;
#pragma unroll 2
  for (int i = 0; i < 32; i++) {
    unsigned long long mwd = mask[(size_t)p * NW + i];
    int q = i * 64 + lane;
    if ((mwd >> lane) & 1ull) {
      float e = s1h[q] + s2p;
      e = fmaxf(e, ALPHA * e);
      float w = __expf(e - mhv);
      const float* __restrict__ hq = h2 + ((size_t)head * N + q) * 3;
      a0 = fmaf(w, hq[0], a0);
      a1 = fmaf(w, hq[1], a1);
      a2 = fmaf(w, hq[2], a2);
      wsum += w;
    }
  }
  for (int s = 32; s; s >>= 1) {
    a0 += __shfl_xor(a0, s); a1 += __shfl_xor(a1, s);
    a2 += __shfl_xor(a2, s); wsum += __shfl_xor(wsum, s);
  }
  __shared__ float red[4][4];
  if (lane == 0) { red[head][0] = a0; red[head][1] = a1; red[head][2] = a2; red[head][3] = wsum; }
  __syncthreads();
  if (threadIdx.x < 3) {
    int f = threadIdx.x;
    float v = 0.f;
#pragma unroll
    for (int hh = 0; hh < 4; hh++) v += red[hh][f] / red[hh][3];
    v *= 0.25f;
    v = v > 0.f ? v : (__expf(v) - 1.f);
    emb[p * 3 + f] = v;
  }
}

// ---------------- all-pairs edge classifier ----------------
__global__ void cls_kernel(const float* __restrict__ emb,
                           const float* __restrict__ W1, const float* __restrict__ b1,
                           const float* __restrict__ W2, const float* __restrict__ b2,
                           float* __restrict__ out) {
  int q = blockIdx.x * 256 + threadIdx.x;
  int p0 = blockIdx.y * 8;
  __shared__ float ep[8][3];
  __shared__ float w1s[96], b1s[32], w2s[32];
  __shared__ float b2s;
  int t = threadIdx.x;
  if (t < 96) w1s[t] = W1[t];
  else if (t < 128) b1s[t - 96] = b1[t - 96];
  else if (t < 160) w2s[t - 128] = W2[t - 128];
  else if (t == 160) b2s = b2[0];
  else if (t >= 192 && t < 216) ((float*)ep)[t - 192] = emb[p0 * 3 + t - 192];
  __syncthreads();
  float e0 = emb[q * 3 + 0], e1 = emb[q * 3 + 1], e2 = emb[q * 3 + 2];
  float d[8][3];
#pragma unroll
  for (int i = 0; i < 8; i++) {
    d[i][0] = fabsf(ep[i][0] - e0);
    d[i][1] = fabsf(ep[i][1] - e1);
    d[i][2] = fabsf(ep[i][2] - e2);
  }
  float acc[8] = {0, 0, 0, 0, 0, 0, 0, 0};
#pragma unroll
  for (int j = 0; j < 32; j++) {
    float c0 = w1s[j], c1 = w1s[32 + j], c2 = w1s[64 + j], bb = b1s[j], w2 = w2s[j];
#pragma unroll
    for (int i = 0; i < 8; i++) {
      float hv = fmaxf(bb + d[i][0] * c0 + d[i][1] * c1 + d[i][2] * c2, 0.f);
      acc[i] += hv * w2;
    }
  }
#pragma unroll
  for (int i = 0; i < 8; i++) {
    float x = acc[i] + b2s;
    out[(size_t)(p0 + i) * N + q] = 1.f / (1.f + __expf(-x));
  }
}

extern "C" void kernel_launch(void* const* d_in, const int* in_sizes, int n_in,
                              void* d_out, int out_size, void* d_ws, size_t ws_size,
                              hipStream_t stream) {
  const float* nf    = (const float*)d_in[0];
  const int*   adj   = (const int*)d_in[1];
  const float* encW1 = (const float*)d_in[2];
  const float* encb1 = (const float*)d_in[3];
  const float* encW2 = (const float*)d_in[4];
  const float* encb2 = (const float*)d_in[5];
  const float* gatW0 = (const float*)d_in[6];
  const float* gata0 = (const float*)d_in[7];
  const float* gatW1 = (const float*)d_in[8];
  const float* gata1 = (const float*)d_in[9];
  const float* gatW2 = (const float*)d_in[10];
  const float* gata2 = (const float*)d_in[11];
  const float* clsW1 = (const float*)d_in[12];
  const float* clsb1 = (const float*)d_in[13];
  const float* clsW2 = (const float*)d_in[14];
  const float* clsb2 = (const float*)d_in[15];

  float* ws = (float*)d_ws;
  // sizes in floats
  unsigned short* hT   = (unsigned short*)ws;              // 4*64*2048 sh = 262144 f
  float* s1   = ws + 262144;                               // 8192
  float* s2   = s1 + 8192;                                 // 8192
  float* pm1  = s2 + 8192;                                 // 512
  float* pm1h3= pm1 + 512;                                 // 2048
  unsigned short* x0hi = (unsigned short*)(pm1h3 + 2048);  // 2048*64 sh = 65536 f
  unsigned short* x0lo = x0hi + 131072;                    // 65536 f
  unsigned short* wt0hi= x0lo + 131072;                    // 16384 sh = 8192 f
  unsigned short* wt0lo= wt0hi + 16384;                    // 8192 f
  unsigned short* wt1hi= wt0lo + 16384;                    // 65536 sh = 32768 f
  unsigned short* wt1lo= wt1hi + 65536;                    // 32768 f
  float* xA   = (float*)(wt1lo + 65536);                   // 524288 f
  unsigned short* xAhi = (unsigned short*)(xA + 524288);   // 2048*256 sh = 262144 f
  unsigned short* xAlo = xAhi + 524288;                    // 262144 f
  float* xB   = (float*)xAhi;                              // alias: xAhi/lo dead after proj L1
  float* h2   = (float*)(xAlo + 524288);                   // 24576 f
  unsigned long long* mask = (unsigned long long*)(h2 + 24576); // 65536 ull = 131072 f

  float* emb = (float*)d_out;
  float* eprob = emb + N * 3;

  pack_adj_kernel<<<dim3(N * NW / 4), dim3(256), 0, stream>>>(adj, mask);
  wprep_kernel<<<dim3(20), dim3(256), 0, stream>>>(gatW0, gatW1, wt0hi, wt0lo, wt1hi, wt1lo);
  enc_kernel<<<dim3(N / 4), dim3(256), 0, stream>>>(nf, encW1, encb1, encW2, encb2, x0hi, x0lo);

  // ---- GAT layer 0 ----
  proj_mfma_kernel<64><<<dim3(N / 16, H), dim3(256), 0, stream>>>(
      x0hi, x0lo, wt0hi, wt0lo, gata0, hT, s1, s2, pm1);
  agg_fused_kernel<<<dim3(N / 16, H), dim3(512), 0, stream>>>(
      hT, s1, s2, pm1, mask, xA, xAhi, xAlo);

  // ---- GAT layer 1 ----
  proj_mfma_kernel<256><<<dim3(N / 16, H), dim3(256), 0, stream>>>(
      xAhi, xAlo, wt1hi, wt1lo, gata1, hT, s1, s2, pm1);
  agg_fused_kernel<<<dim3(N / 16, H), dim3(512), 0, stream>>>(
      hT, s1, s2, pm1, mask, xB, (unsigned short*)nullptr, (unsigned short*)nullptr);

  // ---- GAT layer 2 ----
  h3_kernel<<<dim3(N / 4), dim3(256), 0, stream>>>(xB, gatW2, gata2, h2, s1, s2, pm1h3);
  agg2_kernel<<<dim3(N), dim3(256), 0, stream>>>(h2, s1, s2, pm1h3, mask, emb);

  // ---- classifier ----
  cls_kernel<<<dim3(8, N / 8), dim3(256), 0, stream>>>(emb, clsW1, clsb1, clsW2, clsb2, eprob);
}